// Round 2
// baseline (135072.437 us; speedup 1.0000x reference)
//
#include <hip/hip_runtime.h>
#include <hip/hip_bf16.h>
#include <stdint.h>

// ---------------------------------------------------------------------------
// Pointer-network decoder: 512 sequential steps, B=128 independent batch rows.
// One workgroup per batch row runs the whole scan (no grid sync needed).
// Sampling must reproduce jax.random.categorical bit-stream (Threefry-2x32).
// PARTITIONABLE=1 -> modern JAX default (threefry_partitionable=True).
// Outputs are fp32 (reference returns fp32; round-1 absmax=512.0 artifact was
// bf16 writes being decoded as fp32 by the harness).
// ---------------------------------------------------------------------------

#define PARTITIONABLE 1

#define B_ 128
#define L_ 512
#define E_ 128
#define H_ 256
#define G4_ 1024

__device__ __forceinline__ void tf2x32(uint32_t k0, uint32_t k1,
                                       uint32_t x0, uint32_t x1,
                                       uint32_t &o0, uint32_t &o1) {
  uint32_t ks2 = k0 ^ k1 ^ 0x1BD11BDAu;
#define TFR(a, b, r) { a += b; b = (b << (r)) | (b >> (32 - (r))); b ^= a; }
  x0 += k0; x1 += k1;
  TFR(x0, x1, 13) TFR(x0, x1, 15) TFR(x0, x1, 26) TFR(x0, x1, 6)
  x0 += k1; x1 += ks2 + 1u;
  TFR(x0, x1, 17) TFR(x0, x1, 29) TFR(x0, x1, 16) TFR(x0, x1, 24)
  x0 += ks2; x1 += k0 + 2u;
  TFR(x0, x1, 13) TFR(x0, x1, 15) TFR(x0, x1, 26) TFR(x0, x1, 6)
  x0 += k0; x1 += k1 + 3u;
  TFR(x0, x1, 17) TFR(x0, x1, 29) TFR(x0, x1, 16) TFR(x0, x1, 24)
  x0 += k1; x1 += ks2 + 4u;
  TFR(x0, x1, 13) TFR(x0, x1, 15) TFR(x0, x1, 26) TFR(x0, x1, 6)
  x0 += ks2; x1 += k0 + 5u;
#undef TFR
  o0 = x0; o1 = x1;
}

// keys = jax.random.split(jax.random.key(42), 512); key(42) = (0, 42)
__device__ __forceinline__ void step_key(int t, uint32_t &k0, uint32_t &k1) {
#if PARTITIONABLE
  // foldlike split: keys[t] = threefry(root, (hi=0, lo=t))
  tf2x32(0u, 42u, 0u, (uint32_t)t, k0, k1);
#else
  // original split: counts = iota(1024) halves x0=[0..511], x1=[512..1023]
  // out = concat(o0(len512), o1(len512)); keys[t] = (out[2t], out[2t+1])
  uint32_t d0, d1;
  uint32_t i = 2u * (uint32_t)t;
  if (t < 256) {
    tf2x32(0u, 42u, i,      512u + i, k0, d1);
    tf2x32(0u, 42u, i + 1u, 513u + i, k1, d1);
  } else {
    tf2x32(0u, 42u, i - 512u, i,      d0, k0);
    tf2x32(0u, 42u, i - 511u, i + 1u, d0, k1);
  }
#endif
}

// gumbel sample for flat element j of shape (B, L): j = b*512 + l
__device__ __forceinline__ float gumbel_for(uint32_t k0, uint32_t k1, uint32_t j) {
  uint32_t bits, o0, o1;
#if PARTITIONABLE
  tf2x32(k0, k1, 0u, j, o0, o1);
  bits = o0 ^ o1;
#else
  // original random_bits: iota(65536) halves: pairs (j, 32768+j)
  if (j < 32768u) { tf2x32(k0, k1, j, j + 32768u, o0, o1); bits = o0; }
  else            { tf2x32(k0, k1, j - 32768u, j, o0, o1); bits = o1; }
#endif
  float f = __uint_as_float((bits >> 9) | 0x3f800000u) - 1.0f;
  float u = (f > 0.0f) ? f : 1.1754943508222875e-38f;
  return -logf(-logf(u));
}

__device__ __forceinline__ float sigmoidf_(float x) {
  return 1.0f / (1.0f + expf(-x));
}

// ---------------------------------------------------------------------------
// Kernel A: ctxT[b][k][l] = sum_j context[b][l][j] * W_ctx[j][k] + b_ctx[k]
// ---------------------------------------------------------------------------
__global__ __launch_bounds__(256, 2) void ctx_precompute(
    const float* __restrict__ context, const float* __restrict__ Wctx,
    const float* __restrict__ bctx, float* __restrict__ ctxT) {
  __shared__ float lctx[64][256];  // 64 KB
  int b = blockIdx.x >> 3;
  int l0 = (blockIdx.x & 7) << 6;
  const float* src = context + ((size_t)b * L_ + l0) * H_;
  for (int i = threadIdx.x; i < 64 * 256; i += 256)
    lctx[i >> 8][i & 255] = src[i];
  __syncthreads();
  int k = threadIdx.x;
  float bk = bctx[k];
  for (int g = 0; g < 8; ++g) {
    float acc[8] = {0, 0, 0, 0, 0, 0, 0, 0};
    for (int j = 0; j < H_; ++j) {
      float w = Wctx[(size_t)j * H_ + k];   // coalesced across k
#pragma unroll
      for (int i = 0; i < 8; ++i) acc[i] = fmaf(lctx[g * 8 + i][j], w, acc[i]);
    }
    float* dst = ctxT + ((size_t)b * H_ + k) * L_ + l0 + g * 8;
#pragma unroll
    for (int i = 0; i < 8; ++i) dst[i] = acc[i] + bk;
  }
}

// ---------------------------------------------------------------------------
// Kernel B: full 512-step scan. One block per batch row, 512 threads (8 waves).
// ---------------------------------------------------------------------------
__global__ __launch_bounds__(512, 1) void decoder_scan(
    const float* __restrict__ embedded, const float* __restrict__ dec_in,
    const float* __restrict__ h0, const float* __restrict__ c0,
    const float* __restrict__ Wih, const float* __restrict__ bih,
    const float* __restrict__ Whh, const float* __restrict__ bhh,
    const float* __restrict__ Wout, const float* __restrict__ bout,
    const float* __restrict__ Winp, const float* __restrict__ binp,
    const float* __restrict__ Vv, const float* __restrict__ ctxT,
    float* __restrict__ out) {
  __shared__ float sh[H_], sc[H_], sht[H_], sx[E_], sinp[H_], shs[H_];
  __shared__ float salpha[L_], smask[L_];
  __shared__ float sgates[G4_];
  __shared__ float sV[H_], sbih[G4_], sbhh[G4_], sbout[H_], sbinp[H_];
  __shared__ float redp[8];
  __shared__ int redpi[8];
  __shared__ float red_res;
  __shared__ int red_resi;

  const int tid = threadIdx.x;
  const int b = blockIdx.x;
  const int lane = tid & 63, wid = tid >> 6;

  if (tid < H_) {
    sh[tid] = h0[b * H_ + tid];
    sc[tid] = c0[b * H_ + tid];
    sV[tid] = Vv[tid];
    sbout[tid] = bout[tid];
    sbinp[tid] = binp[tid];
  }
  if (tid < E_) sx[tid] = dec_in[b * E_ + tid];
  smask[tid] = 1.0f;
  sbih[tid] = bih[tid]; sbih[tid + 512] = bih[tid + 512];
  sbhh[tid] = bhh[tid]; sbhh[tid + 512] = bhh[tid + 512];
  __syncthreads();

  const float* ctb = ctxT + (size_t)b * H_ * L_;          // [k][l]
  float* outA = out + (size_t)b * L_ * L_;
  float* outP = out + (size_t)B_ * L_ * L_ + (size_t)b * L_;
  float* outH = out + (size_t)B_ * L_ * L_ + (size_t)B_ * L_ + (size_t)b * H_;
  float* outC = outH + (size_t)B_ * H_;

  for (int t = 0; t < L_; ++t) {
    // ---- phase 1: gates[j] = x@W_ih + b_ih + h@W_hh + b_hh  (2 cols/thread)
    {
      int j0 = tid, j1 = tid + 512;
      float a00 = 0, a01 = 0, a02 = 0, a03 = 0, a10 = 0, a11 = 0, a12 = 0, a13 = 0;
      for (int k = 0; k < E_; k += 4) {
        float x0 = sx[k], x1 = sx[k + 1], x2 = sx[k + 2], x3 = sx[k + 3];
        const float* w = Wih + (size_t)k * G4_;
        a00 = fmaf(x0, w[j0], a00);            a10 = fmaf(x0, w[j1], a10);
        a01 = fmaf(x1, w[G4_ + j0], a01);      a11 = fmaf(x1, w[G4_ + j1], a11);
        a02 = fmaf(x2, w[2 * G4_ + j0], a02);  a12 = fmaf(x2, w[2 * G4_ + j1], a12);
        a03 = fmaf(x3, w[3 * G4_ + j0], a03);  a13 = fmaf(x3, w[3 * G4_ + j1], a13);
      }
      float g0 = ((a00 + a01) + (a02 + a03)) + sbih[j0];
      float g1 = ((a10 + a11) + (a12 + a13)) + sbih[j1];
      a00 = a01 = a02 = a03 = a10 = a11 = a12 = a13 = 0.f;
      for (int k = 0; k < H_; k += 4) {
        float h0v = sh[k], h1v = sh[k + 1], h2v = sh[k + 2], h3v = sh[k + 3];
        const float* w = Whh + (size_t)k * G4_;
        a00 = fmaf(h0v, w[j0], a00);            a10 = fmaf(h0v, w[j1], a10);
        a01 = fmaf(h1v, w[G4_ + j0], a01);      a11 = fmaf(h1v, w[G4_ + j1], a11);
        a02 = fmaf(h2v, w[2 * G4_ + j0], a02);  a12 = fmaf(h2v, w[2 * G4_ + j1], a12);
        a03 = fmaf(h3v, w[3 * G4_ + j0], a03);  a13 = fmaf(h3v, w[3 * G4_ + j1], a13);
      }
      sgates[j0] = (g0 + ((a00 + a01) + (a02 + a03))) + sbhh[j0];
      sgates[j1] = (g1 + ((a10 + a11) + (a12 + a13))) + sbhh[j1];
    }
    __syncthreads();

    // ---- phase 2: LSTM pointwise
    if (tid < H_) {
      float ig = sgates[tid], fg = sgates[H_ + tid];
      float gg = sgates[2 * H_ + tid], og = sgates[3 * H_ + tid];
      float ct = sigmoidf_(fg) * sc[tid] + sigmoidf_(ig) * tanhf(gg);
      sc[tid] = ct;
      sht[tid] = sigmoidf_(og) * tanhf(ct);
    }
    __syncthreads();

    // ---- phase 3: inp = h_t @ W_inp + b_inp
    if (tid < H_) {
      float a0 = 0, a1 = 0, a2 = 0, a3 = 0;
      for (int j = 0; j < H_; j += 4) {
        a0 = fmaf(sht[j],     Winp[(size_t)j * H_ + tid], a0);
        a1 = fmaf(sht[j + 1], Winp[(size_t)(j + 1) * H_ + tid], a1);
        a2 = fmaf(sht[j + 2], Winp[(size_t)(j + 2) * H_ + tid], a2);
        a3 = fmaf(sht[j + 3], Winp[(size_t)(j + 3) * H_ + tid], a3);
      }
      sinp[tid] = ((a0 + a1) + (a2 + a3)) + sbinp[tid];
    }
    __syncthreads();

    // ---- phase 4: att_l = sum_k V[k]*tanh(inp[k] + ctx[l][k]), masked -> -inf
    float attl;
    {
      int l = tid;
      float a0 = 0, a1 = 0, a2 = 0, a3 = 0;
      for (int k = 0; k < H_; k += 4) {
        float t0 = tanhf(sinp[k]     + ctb[(size_t)k * L_ + l]);
        float t1 = tanhf(sinp[k + 1] + ctb[(size_t)(k + 1) * L_ + l]);
        float t2 = tanhf(sinp[k + 2] + ctb[(size_t)(k + 2) * L_ + l]);
        float t3 = tanhf(sinp[k + 3] + ctb[(size_t)(k + 3) * L_ + l]);
        a0 = fmaf(sV[k], t0, a0);     a1 = fmaf(sV[k + 1], t1, a1);
        a2 = fmaf(sV[k + 2], t2, a2); a3 = fmaf(sV[k + 3], t3, a3);
      }
      float av = (a0 + a1) + (a2 + a3);
      attl = (smask[tid] > 0.0f) ? av : -__builtin_inff();
    }

    // ---- phase 5: softmax (max-reduce, exp, sum-reduce)
    {
      float v = attl;
      for (int o = 32; o > 0; o >>= 1) v = fmaxf(v, __shfl_xor(v, o, 64));
      if (lane == 0) redp[wid] = v;
      __syncthreads();
      if (tid == 0) {
        float m = redp[0];
#pragma unroll
        for (int w = 1; w < 8; ++w) m = fmaxf(m, redp[w]);
        red_res = m;
      }
      __syncthreads();
    }
    float m = red_res;
    float e = expf(attl - m);
    {
      float v = e;
      for (int o = 32; o > 0; o >>= 1) v += __shfl_xor(v, o, 64);
      if (lane == 0) redp[wid] = v;
      __syncthreads();
      if (tid == 0)
        red_res = ((redp[0] + redp[1]) + (redp[2] + redp[3])) +
                  ((redp[4] + redp[5]) + (redp[6] + redp[7]));
      __syncthreads();
    }
    float S = red_res;
    float al = e / S;
    salpha[tid] = al;
    outA[(size_t)t * L_ + tid] = al;
    __syncthreads();

    // ---- phase 5b: hs[k] = sum_l alpha[l] * ctx[l][k]  (wave-per-k, coalesced)
    {
      for (int mm = 0; mm < 32; ++mm) {
        int k = wid * 32 + mm;
        const float* cr = ctb + (size_t)k * L_;
        float a = 0;
#pragma unroll
        for (int cch = 0; cch < 8; ++cch) {
          int l = lane + (cch << 6);
          a = fmaf(salpha[l], cr[l], a);
        }
        for (int o = 32; o > 0; o >>= 1) a += __shfl_xor(a, o, 64);
        if (lane == 0) shs[k] = a;
      }
    }

    // ---- phase 6: sampling: argmax_l( log(alpha*mask) + gumbel )
    {
      uint32_t k0, k1;
      step_key(t, k0, k1);
      float g = gumbel_for(k0, k1, (uint32_t)(b * L_ + tid));
      float pl = salpha[tid] * smask[tid];
      float sv = logf(pl) + g;
      int si = tid;
      for (int o = 32; o > 0; o >>= 1) {
        float ov = __shfl_xor(sv, o, 64);
        int oi = __shfl_xor(si, o, 64);
        if (ov > sv || (ov == sv && oi < si)) { sv = ov; si = oi; }
      }
      if (lane == 0) { redp[wid] = sv; redpi[wid] = si; }
      __syncthreads();
      if (tid == 0) {
        float bv = redp[0];
        int bi = redpi[0];
#pragma unroll
        for (int w = 1; w < 8; ++w) {
          if (redp[w] > bv || (redp[w] == bv && redpi[w] < bi)) {
            bv = redp[w]; bi = redpi[w];
          }
        }
        red_resi = bi;
        smask[bi] = 0.0f;            // mask update
        outP[t] = (float)bi;         // pointer output (fp32)
      }
      __syncthreads();
    }
    int idx = red_resi;

    // ---- phase 7: x <- embedded[b, idx, :]
    if (tid < E_) sx[tid] = embedded[((size_t)b * L_ + idx) * E_ + tid];

    // ---- phase 8: h <- tanh([hs, h_t] @ W_out + b_out)
    if (tid < H_) {
      float a0 = 0, a1 = 0, a2 = 0, a3 = 0;
      for (int r = 0; r < H_; r += 4) {
        a0 = fmaf(shs[r],     Wout[(size_t)r * H_ + tid], a0);
        a1 = fmaf(shs[r + 1], Wout[(size_t)(r + 1) * H_ + tid], a1);
        a2 = fmaf(shs[r + 2], Wout[(size_t)(r + 2) * H_ + tid], a2);
        a3 = fmaf(shs[r + 3], Wout[(size_t)(r + 3) * H_ + tid], a3);
      }
      for (int r = 0; r < H_; r += 4) {
        a0 = fmaf(sht[r],     Wout[(size_t)(H_ + r) * H_ + tid], a0);
        a1 = fmaf(sht[r + 1], Wout[(size_t)(H_ + r + 1) * H_ + tid], a1);
        a2 = fmaf(sht[r + 2], Wout[(size_t)(H_ + r + 2) * H_ + tid], a2);
        a3 = fmaf(sht[r + 3], Wout[(size_t)(H_ + r + 3) * H_ + tid], a3);
      }
      sh[tid] = tanhf((((a0 + a1) + (a2 + a3))) + sbout[tid]);
    }
    __syncthreads();
  }

  if (tid < H_) {
    outH[tid] = sh[tid];
    outC[tid] = sc[tid];
  }
}

extern "C" void kernel_launch(void* const* d_in, const int* in_sizes, int n_in,
                              void* d_out, int out_size, void* d_ws, size_t ws_size,
                              hipStream_t stream) {
  const float* embedded = (const float*)d_in[0];
  const float* dec      = (const float*)d_in[1];
  const float* h0       = (const float*)d_in[2];
  const float* c0       = (const float*)d_in[3];
  const float* context  = (const float*)d_in[4];
  const float* Wih      = (const float*)d_in[5];
  const float* bih      = (const float*)d_in[6];
  const float* Whh      = (const float*)d_in[7];
  const float* bhh      = (const float*)d_in[8];
  const float* Wout     = (const float*)d_in[9];
  const float* bout     = (const float*)d_in[10];
  const float* Winp     = (const float*)d_in[11];
  const float* binp     = (const float*)d_in[12];
  const float* Wctx     = (const float*)d_in[13];
  const float* bctx     = (const float*)d_in[14];
  const float* V        = (const float*)d_in[15];

  size_t ctx_bytes = (size_t)B_ * H_ * L_ * sizeof(float);  // 64 MB
  if (ws_size < ctx_bytes) return;  // cannot proceed without scratch
  float* ctxT = (float*)d_ws;

  ctx_precompute<<<dim3(B_ * 8), dim3(256), 0, stream>>>(context, Wctx, bctx, ctxT);
  decoder_scan<<<dim3(B_), dim3(512), 0, stream>>>(
      embedded, dec, h0, c0, Wih, bih, Whh, bhh, Wout, bout, Winp, binp, V,
      ctxT, (float*)d_out);
}

// Round 3
// 78626.447 us; speedup vs baseline: 1.7179x; 1.7179x over previous
//
#include <hip/hip_runtime.h>
#include <hip/hip_bf16.h>
#include <stdint.h>

// ---------------------------------------------------------------------------
// Pointer-network decoder, multi-kernel full-chip version.
// 512 sequential steps; each step = 5 chip-wide kernels communicating via ws.
// All floating-point reductions replicate the EXACT accumulation structure and
// order of the previously-passing single-kernel version -> bit-identical
// outputs (pointer stream must not flip). Falls back to the single-kernel
// persistent path if ws is too small.
// ---------------------------------------------------------------------------

#define PARTITIONABLE 1

#define B_ 128
#define L_ 512
#define E_ 128
#define H_ 256
#define G4_ 1024

// ---------------- Threefry-2x32 (exact JAX reproduction) -------------------
__device__ __forceinline__ void tf2x32(uint32_t k0, uint32_t k1,
                                       uint32_t x0, uint32_t x1,
                                       uint32_t &o0, uint32_t &o1) {
  uint32_t ks2 = k0 ^ k1 ^ 0x1BD11BDAu;
#define TFR(a, b, r) { a += b; b = (b << (r)) | (b >> (32 - (r))); b ^= a; }
  x0 += k0; x1 += k1;
  TFR(x0, x1, 13) TFR(x0, x1, 15) TFR(x0, x1, 26) TFR(x0, x1, 6)
  x0 += k1; x1 += ks2 + 1u;
  TFR(x0, x1, 17) TFR(x0, x1, 29) TFR(x0, x1, 16) TFR(x0, x1, 24)
  x0 += ks2; x1 += k0 + 2u;
  TFR(x0, x1, 13) TFR(x0, x1, 15) TFR(x0, x1, 26) TFR(x0, x1, 6)
  x0 += k0; x1 += k1 + 3u;
  TFR(x0, x1, 17) TFR(x0, x1, 29) TFR(x0, x1, 16) TFR(x0, x1, 24)
  x0 += k1; x1 += ks2 + 4u;
  TFR(x0, x1, 13) TFR(x0, x1, 15) TFR(x0, x1, 26) TFR(x0, x1, 6)
  x0 += ks2; x1 += k0 + 5u;
#undef TFR
  o0 = x0; o1 = x1;
}

__device__ __forceinline__ void step_key(int t, uint32_t &k0, uint32_t &k1) {
#if PARTITIONABLE
  tf2x32(0u, 42u, 0u, (uint32_t)t, k0, k1);
#else
  uint32_t d0, d1;
  uint32_t i = 2u * (uint32_t)t;
  if (t < 256) {
    tf2x32(0u, 42u, i,      512u + i, k0, d1);
    tf2x32(0u, 42u, i + 1u, 513u + i, k1, d1);
  } else {
    tf2x32(0u, 42u, i - 512u, i,      d0, k0);
    tf2x32(0u, 42u, i - 511u, i + 1u, d0, k1);
  }
#endif
}

__device__ __forceinline__ float gumbel_for(uint32_t k0, uint32_t k1, uint32_t j) {
  uint32_t bits, o0, o1;
#if PARTITIONABLE
  tf2x32(k0, k1, 0u, j, o0, o1);
  bits = o0 ^ o1;
#else
  if (j < 32768u) { tf2x32(k0, k1, j, j + 32768u, o0, o1); bits = o0; }
  else            { tf2x32(k0, k1, j - 32768u, j, o0, o1); bits = o1; }
#endif
  float f = __uint_as_float((bits >> 9) | 0x3f800000u) - 1.0f;
  float u = (f > 0.0f) ? f : 1.1754943508222875e-38f;
  return -logf(-logf(u));
}

__device__ __forceinline__ float sigmoidf_(float x) {
  return 1.0f / (1.0f + expf(-x));
}

// ---------------------------------------------------------------------------
// ctx precompute: ctxT[b][k][l] = sum_j context[b][l][j]*W_ctx[j][k] + b_ctx[k]
// ---------------------------------------------------------------------------
__global__ __launch_bounds__(256, 2) void ctx_precompute(
    const float* __restrict__ context, const float* __restrict__ Wctx,
    const float* __restrict__ bctx, float* __restrict__ ctxT) {
  __shared__ float lctx[64][256];
  int b = blockIdx.x >> 3;
  int l0 = (blockIdx.x & 7) << 6;
  const float* src = context + ((size_t)b * L_ + l0) * H_;
  for (int i = threadIdx.x; i < 64 * 256; i += 256)
    lctx[i >> 8][i & 255] = src[i];
  __syncthreads();
  int k = threadIdx.x;
  float bk = bctx[k];
  for (int g = 0; g < 8; ++g) {
    float acc[8] = {0, 0, 0, 0, 0, 0, 0, 0};
    for (int j = 0; j < H_; ++j) {
      float w = Wctx[(size_t)j * H_ + k];
#pragma unroll
      for (int i = 0; i < 8; ++i) acc[i] = fmaf(lctx[g * 8 + i][j], w, acc[i]);
    }
    float* dst = ctxT + ((size_t)b * H_ + k) * L_ + l0 + g * 8;
#pragma unroll
    for (int i = 0; i < 8; ++i) dst[i] = acc[i] + bk;
  }
}

// ---------------------------------------------------------------------------
// K0: init carried state in ws
// ---------------------------------------------------------------------------
__global__ __launch_bounds__(512) void k_init(
    const float* __restrict__ h0, const float* __restrict__ c0,
    const float* __restrict__ dec, float* __restrict__ h,
    float* __restrict__ c, float* __restrict__ mk, float* __restrict__ x) {
  int b = blockIdx.x, tid = threadIdx.x;
  if (tid < H_) { h[b * H_ + tid] = h0[b * H_ + tid]; c[b * H_ + tid] = c0[b * H_ + tid]; }
  if (tid < E_) x[b * E_ + tid] = dec[b * E_ + tid];
  mk[b * L_ + tid] = 1.0f;
}

// ---------------------------------------------------------------------------
// K1: gates[b][j] = x@Wih + bih + h@Whh + bhh   (thread per (b,j))
// grid 512 = (b*4 + jslice), 256 threads
// ---------------------------------------------------------------------------
__global__ __launch_bounds__(256) void k_gates(
    const float* __restrict__ Wih, const float* __restrict__ bih,
    const float* __restrict__ Whh, const float* __restrict__ bhh,
    const float* __restrict__ x, const float* __restrict__ h,
    float* __restrict__ gates) {
  __shared__ float sx[E_], sh[H_];
  int b = blockIdx.x >> 2;
  int j = ((blockIdx.x & 3) << 8) + threadIdx.x;
  int tid = threadIdx.x;
  sh[tid] = h[b * H_ + tid];
  if (tid < E_) sx[tid] = x[b * E_ + tid];
  __syncthreads();
  float a0 = 0, a1 = 0, a2 = 0, a3 = 0;
#pragma unroll 4
  for (int k = 0; k < E_; k += 4) {
    const float* w = Wih + (size_t)k * G4_ + j;
    a0 = fmaf(sx[k],     w[0],        a0);
    a1 = fmaf(sx[k + 1], w[G4_],      a1);
    a2 = fmaf(sx[k + 2], w[2 * G4_],  a2);
    a3 = fmaf(sx[k + 3], w[3 * G4_],  a3);
  }
  float g0 = ((a0 + a1) + (a2 + a3)) + bih[j];
  a0 = a1 = a2 = a3 = 0.f;
#pragma unroll 4
  for (int k = 0; k < H_; k += 4) {
    const float* w = Whh + (size_t)k * G4_ + j;
    a0 = fmaf(sh[k],     w[0],        a0);
    a1 = fmaf(sh[k + 1], w[G4_],      a1);
    a2 = fmaf(sh[k + 2], w[2 * G4_],  a2);
    a3 = fmaf(sh[k + 3], w[3 * G4_],  a3);
  }
  gates[(size_t)b * G4_ + j] = (g0 + ((a0 + a1) + (a2 + a3))) + bhh[j];
}

// ---------------------------------------------------------------------------
// K2: LSTM pointwise + inp GEMV + attention tanh pass
// grid 256 = (b*2 + lhalf), 256 threads
// ---------------------------------------------------------------------------
__global__ __launch_bounds__(256) void k_lstm_att(
    const float* __restrict__ gates, const float* __restrict__ c_rd,
    float* __restrict__ c_wr, float* __restrict__ ht_ws,
    const float* __restrict__ Winp, const float* __restrict__ binp,
    const float* __restrict__ Vv, const float* __restrict__ ctxT,
    const float* __restrict__ mk, float* __restrict__ att_ws,
    float* __restrict__ out, int t) {
  __shared__ float sht[H_], sinp[H_], sV[H_];
  int b = blockIdx.x >> 1;
  int lh = blockIdx.x & 1;
  int tid = threadIdx.x;

  // pointwise LSTM (both blocks compute; lh==0 persists)
  {
    float ig = gates[(size_t)b * G4_ + tid];
    float fg = gates[(size_t)b * G4_ + H_ + tid];
    float gg = gates[(size_t)b * G4_ + 2 * H_ + tid];
    float og = gates[(size_t)b * G4_ + 3 * H_ + tid];
    float ct = sigmoidf_(fg) * c_rd[b * H_ + tid] + sigmoidf_(ig) * tanhf(gg);
    float htv = sigmoidf_(og) * tanhf(ct);
    sht[tid] = htv;
    if (lh == 0) {
      c_wr[b * H_ + tid] = ct;
      ht_ws[b * H_ + tid] = htv;
      if (t == L_ - 1) {
        float* outC = out + (size_t)B_ * L_ * L_ + (size_t)B_ * L_ +
                      (size_t)B_ * H_ + (size_t)b * H_;
        outC[tid] = ct;
      }
    }
  }
  sV[tid] = Vv[tid];
  __syncthreads();

  // inp = h_t @ W_inp + b_inp (exact 4-acc order)
  {
    float a0 = 0, a1 = 0, a2 = 0, a3 = 0;
#pragma unroll 4
    for (int jv = 0; jv < H_; jv += 4) {
      a0 = fmaf(sht[jv],     Winp[(size_t)jv * H_ + tid],       a0);
      a1 = fmaf(sht[jv + 1], Winp[(size_t)(jv + 1) * H_ + tid], a1);
      a2 = fmaf(sht[jv + 2], Winp[(size_t)(jv + 2) * H_ + tid], a2);
      a3 = fmaf(sht[jv + 3], Winp[(size_t)(jv + 3) * H_ + tid], a3);
    }
    sinp[tid] = ((a0 + a1) + (a2 + a3)) + binp[tid];
  }
  __syncthreads();

  // att logit for l = lh*256 + tid (exact 4-acc order over k)
  {
    int l = (lh << 8) + tid;
    const float* ctb = ctxT + (size_t)b * H_ * L_;
    float a0 = 0, a1 = 0, a2 = 0, a3 = 0;
#pragma unroll 2
    for (int k = 0; k < H_; k += 4) {
      float t0 = tanhf(sinp[k]     + ctb[(size_t)k * L_ + l]);
      float t1 = tanhf(sinp[k + 1] + ctb[(size_t)(k + 1) * L_ + l]);
      float t2 = tanhf(sinp[k + 2] + ctb[(size_t)(k + 2) * L_ + l]);
      float t3 = tanhf(sinp[k + 3] + ctb[(size_t)(k + 3) * L_ + l]);
      a0 = fmaf(sV[k], t0, a0);     a1 = fmaf(sV[k + 1], t1, a1);
      a2 = fmaf(sV[k + 2], t2, a2); a3 = fmaf(sV[k + 3], t3, a3);
    }
    float av = (a0 + a1) + (a2 + a3);
    att_ws[b * L_ + l] = (mk[b * L_ + l] > 0.0f) ? av : -__builtin_inff();
  }
}

// ---------------------------------------------------------------------------
// K3: softmax + alpha out + gumbel sample + mask update + x gather
// grid 128 (b), 512 threads (exact replication of original reductions)
// ---------------------------------------------------------------------------
__global__ __launch_bounds__(512) void k_sample(
    const float* __restrict__ att_ws, float* __restrict__ mk,
    float* __restrict__ alpha_ws, float* __restrict__ x,
    const float* __restrict__ embedded, float* __restrict__ out, int t) {
  __shared__ float redp[8];
  __shared__ int redpi[8];
  __shared__ float red_res;
  __shared__ int red_resi;
  int b = blockIdx.x, tid = threadIdx.x;
  int lane = tid & 63, wid = tid >> 6;

  float attl = att_ws[b * L_ + tid];

  // max reduce (exact structure)
  {
    float v = attl;
    for (int o = 32; o > 0; o >>= 1) v = fmaxf(v, __shfl_xor(v, o, 64));
    if (lane == 0) redp[wid] = v;
    __syncthreads();
    if (tid == 0) {
      float m = redp[0];
#pragma unroll
      for (int w = 1; w < 8; ++w) m = fmaxf(m, redp[w]);
      red_res = m;
    }
    __syncthreads();
  }
  float m = red_res;
  float e = expf(attl - m);
  {
    float v = e;
    for (int o = 32; o > 0; o >>= 1) v += __shfl_xor(v, o, 64);
    if (lane == 0) redp[wid] = v;
    __syncthreads();
    if (tid == 0)
      red_res = ((redp[0] + redp[1]) + (redp[2] + redp[3])) +
                ((redp[4] + redp[5]) + (redp[6] + redp[7]));
    __syncthreads();
  }
  float S = red_res;
  float al = e / S;
  alpha_ws[b * L_ + tid] = al;
  // non-temporal: 134MB streaming output, keep it out of LLC (protect ctxT)
  __builtin_nontemporal_store(al, out + ((size_t)b * L_ + t) * L_ + tid);
  float mval = mk[b * L_ + tid];

  // gumbel-argmax sampling (exact structure)
  {
    uint32_t k0, k1;
    step_key(t, k0, k1);
    float g = gumbel_for(k0, k1, (uint32_t)(b * L_ + tid));
    float pl = al * mval;
    float sv = logf(pl) + g;
    int si = tid;
    for (int o = 32; o > 0; o >>= 1) {
      float ov = __shfl_xor(sv, o, 64);
      int oi = __shfl_xor(si, o, 64);
      if (ov > sv || (ov == sv && oi < si)) { sv = ov; si = oi; }
    }
    if (lane == 0) { redp[wid] = sv; redpi[wid] = si; }
    __syncthreads();
    if (tid == 0) {
      float bv = redp[0];
      int bi = redpi[0];
#pragma unroll
      for (int w = 1; w < 8; ++w) {
        if (redp[w] > bv || (redp[w] == bv && redpi[w] < bi)) {
          bv = redp[w]; bi = redpi[w];
        }
      }
      red_resi = bi;
      mk[b * L_ + bi] = 0.0f;
      out[(size_t)B_ * L_ * L_ + (size_t)b * L_ + t] = (float)bi;
    }
    __syncthreads();
  }
  int idx = red_resi;
  if (tid < E_) x[b * E_ + tid] = embedded[((size_t)b * L_ + idx) * E_ + tid];
}

// ---------------------------------------------------------------------------
// K4: hs[b][k] = sum_l alpha[l]*ctx[k][l]  (exact wave-per-k butterfly)
// grid 256 = (b*2 + khalf), 256 threads (4 waves)
// ---------------------------------------------------------------------------
__global__ __launch_bounds__(256) void k_hs(
    const float* __restrict__ alpha_ws, const float* __restrict__ ctxT,
    float* __restrict__ hs_ws) {
  __shared__ float salpha[L_];
  int b = blockIdx.x >> 1;
  int kh = blockIdx.x & 1;
  int tid = threadIdx.x;
  int lane = tid & 63, wid = tid >> 6;  // wid 0..3
  salpha[tid] = alpha_ws[b * L_ + tid];
  salpha[tid + 256] = alpha_ws[b * L_ + tid + 256];
  __syncthreads();
  const float* ctb = ctxT + (size_t)b * H_ * L_;
  for (int mm = 0; mm < 32; ++mm) {
    int k = (kh * 4 + wid) * 32 + mm;   // matches original wid 0..7 mapping
    const float* cr = ctb + (size_t)k * L_;
    float a = 0;
#pragma unroll
    for (int cch = 0; cch < 8; ++cch) {
      int l = lane + (cch << 6);
      a = fmaf(salpha[l], cr[l], a);
    }
    for (int o = 32; o > 0; o >>= 1) a += __shfl_xor(a, o, 64);
    if (lane == 0) hs_ws[b * H_ + k] = a;
  }
}

// ---------------------------------------------------------------------------
// K5: h_new = tanh([hs, h_t] @ W_out + b_out)  (exact double 4-acc order)
// grid 128 (b), 256 threads
// ---------------------------------------------------------------------------
__global__ __launch_bounds__(256) void k_hnew(
    const float* __restrict__ hs_ws, const float* __restrict__ ht_ws,
    const float* __restrict__ Wout, const float* __restrict__ bout,
    float* __restrict__ h, float* __restrict__ out, int t) {
  __shared__ float shs[H_], sht[H_];
  int b = blockIdx.x, tid = threadIdx.x;
  shs[tid] = hs_ws[b * H_ + tid];
  sht[tid] = ht_ws[b * H_ + tid];
  __syncthreads();
  float a0 = 0, a1 = 0, a2 = 0, a3 = 0;
#pragma unroll 4
  for (int r = 0; r < H_; r += 4) {
    a0 = fmaf(shs[r],     Wout[(size_t)r * H_ + tid],       a0);
    a1 = fmaf(shs[r + 1], Wout[(size_t)(r + 1) * H_ + tid], a1);
    a2 = fmaf(shs[r + 2], Wout[(size_t)(r + 2) * H_ + tid], a2);
    a3 = fmaf(shs[r + 3], Wout[(size_t)(r + 3) * H_ + tid], a3);
  }
#pragma unroll 4
  for (int r = 0; r < H_; r += 4) {
    a0 = fmaf(sht[r],     Wout[(size_t)(H_ + r) * H_ + tid],       a0);
    a1 = fmaf(sht[r + 1], Wout[(size_t)(H_ + r + 1) * H_ + tid],   a1);
    a2 = fmaf(sht[r + 2], Wout[(size_t)(H_ + r + 2) * H_ + tid],   a2);
    a3 = fmaf(sht[r + 3], Wout[(size_t)(H_ + r + 3) * H_ + tid],   a3);
  }
  float hn = tanhf((((a0 + a1) + (a2 + a3))) + bout[tid]);
  h[b * H_ + tid] = hn;
  if (t == L_ - 1) {
    float* outH = out + (size_t)B_ * L_ * L_ + (size_t)B_ * L_ + (size_t)b * H_;
    outH[tid] = hn;
  }
}

// ---------------------------------------------------------------------------
// Fallback: single persistent kernel (previous passing version)
// ---------------------------------------------------------------------------
__global__ __launch_bounds__(512, 1) void decoder_scan(
    const float* __restrict__ embedded, const float* __restrict__ dec_in,
    const float* __restrict__ h0, const float* __restrict__ c0,
    const float* __restrict__ Wih, const float* __restrict__ bih,
    const float* __restrict__ Whh, const float* __restrict__ bhh,
    const float* __restrict__ Wout, const float* __restrict__ bout,
    const float* __restrict__ Winp, const float* __restrict__ binp,
    const float* __restrict__ Vv, const float* __restrict__ ctxT,
    float* __restrict__ out) {
  __shared__ float sh[H_], sc[H_], sht[H_], sx[E_], sinp[H_], shs[H_];
  __shared__ float salpha[L_], smask[L_];
  __shared__ float sgates[G4_];
  __shared__ float sV[H_], sbih[G4_], sbhh[G4_], sbout[H_], sbinp[H_];
  __shared__ float redp[8];
  __shared__ int redpi[8];
  __shared__ float red_res;
  __shared__ int red_resi;

  const int tid = threadIdx.x;
  const int b = blockIdx.x;
  const int lane = tid & 63, wid = tid >> 6;

  if (tid < H_) {
    sh[tid] = h0[b * H_ + tid];
    sc[tid] = c0[b * H_ + tid];
    sV[tid] = Vv[tid];
    sbout[tid] = bout[tid];
    sbinp[tid] = binp[tid];
  }
  if (tid < E_) sx[tid] = dec_in[b * E_ + tid];
  smask[tid] = 1.0f;
  sbih[tid] = bih[tid]; sbih[tid + 512] = bih[tid + 512];
  sbhh[tid] = bhh[tid]; sbhh[tid + 512] = bhh[tid + 512];
  __syncthreads();

  const float* ctb = ctxT + (size_t)b * H_ * L_;
  float* outA = out + (size_t)b * L_ * L_;
  float* outP = out + (size_t)B_ * L_ * L_ + (size_t)b * L_;
  float* outH = out + (size_t)B_ * L_ * L_ + (size_t)B_ * L_ + (size_t)b * H_;
  float* outC = outH + (size_t)B_ * H_;

  for (int t = 0; t < L_; ++t) {
    {
      int j0 = tid, j1 = tid + 512;
      float a00 = 0, a01 = 0, a02 = 0, a03 = 0, a10 = 0, a11 = 0, a12 = 0, a13 = 0;
      for (int k = 0; k < E_; k += 4) {
        float x0 = sx[k], x1 = sx[k + 1], x2 = sx[k + 2], x3 = sx[k + 3];
        const float* w = Wih + (size_t)k * G4_;
        a00 = fmaf(x0, w[j0], a00);            a10 = fmaf(x0, w[j1], a10);
        a01 = fmaf(x1, w[G4_ + j0], a01);      a11 = fmaf(x1, w[G4_ + j1], a11);
        a02 = fmaf(x2, w[2 * G4_ + j0], a02);  a12 = fmaf(x2, w[2 * G4_ + j1], a12);
        a03 = fmaf(x3, w[3 * G4_ + j0], a03);  a13 = fmaf(x3, w[3 * G4_ + j1], a13);
      }
      float g0 = ((a00 + a01) + (a02 + a03)) + sbih[j0];
      float g1 = ((a10 + a11) + (a12 + a13)) + sbih[j1];
      a00 = a01 = a02 = a03 = a10 = a11 = a12 = a13 = 0.f;
      for (int k = 0; k < H_; k += 4) {
        float h0v = sh[k], h1v = sh[k + 1], h2v = sh[k + 2], h3v = sh[k + 3];
        const float* w = Whh + (size_t)k * G4_;
        a00 = fmaf(h0v, w[j0], a00);            a10 = fmaf(h0v, w[j1], a10);
        a01 = fmaf(h1v, w[G4_ + j0], a01);      a11 = fmaf(h1v, w[G4_ + j1], a11);
        a02 = fmaf(h2v, w[2 * G4_ + j0], a02);  a12 = fmaf(h2v, w[2 * G4_ + j1], a12);
        a03 = fmaf(h3v, w[3 * G4_ + j0], a03);  a13 = fmaf(h3v, w[3 * G4_ + j1], a13);
      }
      sgates[j0] = (g0 + ((a00 + a01) + (a02 + a03))) + sbhh[j0];
      sgates[j1] = (g1 + ((a10 + a11) + (a12 + a13))) + sbhh[j1];
    }
    __syncthreads();

    if (tid < H_) {
      float ig = sgates[tid], fg = sgates[H_ + tid];
      float gg = sgates[2 * H_ + tid], og = sgates[3 * H_ + tid];
      float ct = sigmoidf_(fg) * sc[tid] + sigmoidf_(ig) * tanhf(gg);
      sc[tid] = ct;
      sht[tid] = sigmoidf_(og) * tanhf(ct);
    }
    __syncthreads();

    if (tid < H_) {
      float a0 = 0, a1 = 0, a2 = 0, a3 = 0;
      for (int j = 0; j < H_; j += 4) {
        a0 = fmaf(sht[j],     Winp[(size_t)j * H_ + tid], a0);
        a1 = fmaf(sht[j + 1], Winp[(size_t)(j + 1) * H_ + tid], a1);
        a2 = fmaf(sht[j + 2], Winp[(size_t)(j + 2) * H_ + tid], a2);
        a3 = fmaf(sht[j + 3], Winp[(size_t)(j + 3) * H_ + tid], a3);
      }
      sinp[tid] = ((a0 + a1) + (a2 + a3)) + sbinp[tid];
    }
    __syncthreads();

    float attl;
    {
      int l = tid;
      float a0 = 0, a1 = 0, a2 = 0, a3 = 0;
      for (int k = 0; k < H_; k += 4) {
        float t0 = tanhf(sinp[k]     + ctb[(size_t)k * L_ + l]);
        float t1 = tanhf(sinp[k + 1] + ctb[(size_t)(k + 1) * L_ + l]);
        float t2 = tanhf(sinp[k + 2] + ctb[(size_t)(k + 2) * L_ + l]);
        float t3 = tanhf(sinp[k + 3] + ctb[(size_t)(k + 3) * L_ + l]);
        a0 = fmaf(sV[k], t0, a0);     a1 = fmaf(sV[k + 1], t1, a1);
        a2 = fmaf(sV[k + 2], t2, a2); a3 = fmaf(sV[k + 3], t3, a3);
      }
      float av = (a0 + a1) + (a2 + a3);
      attl = (smask[tid] > 0.0f) ? av : -__builtin_inff();
    }

    {
      float v = attl;
      for (int o = 32; o > 0; o >>= 1) v = fmaxf(v, __shfl_xor(v, o, 64));
      if (lane == 0) redp[wid] = v;
      __syncthreads();
      if (tid == 0) {
        float m = redp[0];
#pragma unroll
        for (int w = 1; w < 8; ++w) m = fmaxf(m, redp[w]);
        red_res = m;
      }
      __syncthreads();
    }
    float m = red_res;
    float e = expf(attl - m);
    {
      float v = e;
      for (int o = 32; o > 0; o >>= 1) v += __shfl_xor(v, o, 64);
      if (lane == 0) redp[wid] = v;
      __syncthreads();
      if (tid == 0)
        red_res = ((redp[0] + redp[1]) + (redp[2] + redp[3])) +
                  ((redp[4] + redp[5]) + (redp[6] + redp[7]));
      __syncthreads();
    }
    float S = red_res;
    float al = e / S;
    salpha[tid] = al;
    outA[(size_t)t * L_ + tid] = al;
    __syncthreads();

    {
      for (int mm = 0; mm < 32; ++mm) {
        int k = wid * 32 + mm;
        const float* cr = ctb + (size_t)k * L_;
        float a = 0;
#pragma unroll
        for (int cch = 0; cch < 8; ++cch) {
          int l = lane + (cch << 6);
          a = fmaf(salpha[l], cr[l], a);
        }
        for (int o = 32; o > 0; o >>= 1) a += __shfl_xor(a, o, 64);
        if (lane == 0) shs[k] = a;
      }
    }

    {
      uint32_t k0, k1;
      step_key(t, k0, k1);
      float g = gumbel_for(k0, k1, (uint32_t)(b * L_ + tid));
      float pl = salpha[tid] * smask[tid];
      float sv = logf(pl) + g;
      int si = tid;
      for (int o = 32; o > 0; o >>= 1) {
        float ov = __shfl_xor(sv, o, 64);
        int oi = __shfl_xor(si, o, 64);
        if (ov > sv || (ov == sv && oi < si)) { sv = ov; si = oi; }
      }
      if (lane == 0) { redp[wid] = sv; redpi[wid] = si; }
      __syncthreads();
      if (tid == 0) {
        float bv = redp[0];
        int bi = redpi[0];
#pragma unroll
        for (int w = 1; w < 8; ++w) {
          if (redp[w] > bv || (redp[w] == bv && redpi[w] < bi)) {
            bv = redp[w]; bi = redpi[w];
          }
        }
        red_resi = bi;
        smask[bi] = 0.0f;
        outP[t] = (float)bi;
      }
      __syncthreads();
    }
    int idx = red_resi;

    if (tid < E_) sx[tid] = embedded[((size_t)b * L_ + idx) * E_ + tid];

    if (tid < H_) {
      float a0 = 0, a1 = 0, a2 = 0, a3 = 0;
      for (int r = 0; r < H_; r += 4) {
        a0 = fmaf(shs[r],     Wout[(size_t)r * H_ + tid], a0);
        a1 = fmaf(shs[r + 1], Wout[(size_t)(r + 1) * H_ + tid], a1);
        a2 = fmaf(shs[r + 2], Wout[(size_t)(r + 2) * H_ + tid], a2);
        a3 = fmaf(shs[r + 3], Wout[(size_t)(r + 3) * H_ + tid], a3);
      }
      for (int r = 0; r < H_; r += 4) {
        a0 = fmaf(sht[r],     Wout[(size_t)(H_ + r) * H_ + tid], a0);
        a1 = fmaf(sht[r + 1], Wout[(size_t)(H_ + r + 1) * H_ + tid], a1);
        a2 = fmaf(sht[r + 2], Wout[(size_t)(H_ + r + 2) * H_ + tid], a2);
        a3 = fmaf(sht[r + 3], Wout[(size_t)(H_ + r + 3) * H_ + tid], a3);
      }
      sh[tid] = tanhf((((a0 + a1) + (a2 + a3))) + sbout[tid]);
    }
    __syncthreads();
  }

  if (tid < H_) {
    outH[tid] = sh[tid];
    outC[tid] = sc[tid];
  }
}

// ---------------------------------------------------------------------------
extern "C" void kernel_launch(void* const* d_in, const int* in_sizes, int n_in,
                              void* d_out, int out_size, void* d_ws, size_t ws_size,
                              hipStream_t stream) {
  const float* embedded = (const float*)d_in[0];
  const float* dec      = (const float*)d_in[1];
  const float* h0       = (const float*)d_in[2];
  const float* c0       = (const float*)d_in[3];
  const float* context  = (const float*)d_in[4];
  const float* Wih      = (const float*)d_in[5];
  const float* bih      = (const float*)d_in[6];
  const float* Whh      = (const float*)d_in[7];
  const float* bhh      = (const float*)d_in[8];
  const float* Wout     = (const float*)d_in[9];
  const float* bout     = (const float*)d_in[10];
  const float* Winp     = (const float*)d_in[11];
  const float* binp     = (const float*)d_in[12];
  const float* Wctx     = (const float*)d_in[13];
  const float* bctx     = (const float*)d_in[14];
  const float* V        = (const float*)d_in[15];
  float* out = (float*)d_out;

  float* ws = (float*)d_ws;
  const size_t CTXF = (size_t)B_ * H_ * L_;  // 16,777,216 floats = 64 MB
  float* ctxT  = ws;
  float* gates = ctxT + CTXF;                 // 131072
  float* hbuf  = gates + (size_t)B_ * G4_;    // 32768
  float* cb0   = hbuf + (size_t)B_ * H_;
  float* cb1   = cb0 + (size_t)B_ * H_;
  float* htb   = cb1 + (size_t)B_ * H_;
  float* xb    = htb + (size_t)B_ * H_;       // 16384
  float* attb  = xb + (size_t)B_ * E_;        // 65536
  float* alb   = attb + (size_t)B_ * L_;
  float* mkb   = alb + (size_t)B_ * L_;
  float* hsb   = mkb + (size_t)B_ * L_;       // 32768
  size_t need_f = (size_t)(hsb + (size_t)B_ * H_ - ws);
  size_t need_bytes = need_f * sizeof(float);

  if (ws_size >= need_bytes) {
    // fast multi-kernel path
    ctx_precompute<<<dim3(B_ * 8), dim3(256), 0, stream>>>(context, Wctx, bctx, ctxT);
    k_init<<<dim3(B_), dim3(512), 0, stream>>>(h0, c0, dec, hbuf, cb0, mkb, xb);
    for (int t = 0; t < L_; ++t) {
      float* crd = (t & 1) ? cb1 : cb0;
      float* cwr = (t & 1) ? cb0 : cb1;
      k_gates<<<dim3(B_ * 4), dim3(256), 0, stream>>>(Wih, bih, Whh, bhh, xb, hbuf, gates);
      k_lstm_att<<<dim3(B_ * 2), dim3(256), 0, stream>>>(
          gates, crd, cwr, htb, Winp, binp, V, ctxT, mkb, attb, out, t);
      k_sample<<<dim3(B_), dim3(512), 0, stream>>>(attb, mkb, alb, xb, embedded, out, t);
      k_hs<<<dim3(B_ * 2), dim3(256), 0, stream>>>(alb, ctxT, hsb);
      k_hnew<<<dim3(B_), dim3(256), 0, stream>>>(hsb, htb, Wout, bout, hbuf, out, t);
    }
  } else if (ws_size >= CTXF * sizeof(float)) {
    // fallback: previous passing single-kernel path
    ctx_precompute<<<dim3(B_ * 8), dim3(256), 0, stream>>>(context, Wctx, bctx, ctxT);
    decoder_scan<<<dim3(B_), dim3(512), 0, stream>>>(
        embedded, dec, h0, c0, Wih, bih, Whh, bhh, Wout, bout, Winp, binp, V,
        ctxT, out);
  }
}